// Round 19
// baseline (478.578 us; speedup 1.0000x reference)
//
#include <hip/hip_runtime.h>
#include <stdint.h>

#define B_ROWS 2048
#define D2_DIM 256
#define D_DIM 128
#define M_ITEMS 100000
#define M_PAD 100352           // 196 * 512
#define BN_EPS_F 1e-5f
#define COS_EPS_F 1e-6f
#define LEAKY_F 0.01f

#define CHUNK 512              // items per block (16 stripes of 32)
#define BROWS 128              // rows per block (4 waves x 32)

typedef __bf16 bf16x8 __attribute__((ext_vector_type(8)));
typedef float f32x4 __attribute__((ext_vector_type(4)));

// bf16 hi/lo split planes (device globals; rebuilt every call)
__device__ unsigned short g_Aph[B_ROWS * D_DIM];
__device__ unsigned short g_Apl[B_ROWS * D_DIM];
__device__ unsigned short g_Bph[M_PAD * D_DIM];
__device__ unsigned short g_Bpl[M_PAD * D_DIM];

__device__ __forceinline__ unsigned bf16_rne(float f) {
  unsigned u = __float_as_uint(f);
  return (u + 0x7fffu + ((u >> 16) & 1u)) >> 16;
}
__device__ __forceinline__ void split_bf16(float v, unsigned short& hi, unsigned short& lo) {
  unsigned h = bf16_rne(v);
  float hf = __uint_as_float(h << 16);
  unsigned l = bf16_rne(v - hf);   // exact residual
  hi = (unsigned short)h; lo = (unsigned short)l;
}
__device__ __forceinline__ unsigned long long pack_key(float v, int idx) {
  unsigned u = __float_as_uint(v);
  u = (u & 0x80000000u) ? ~u : (u | 0x80000000u);
  return ((unsigned long long)u << 32) | (unsigned)(~(unsigned)idx);
}

// ---------- kernel 1: h = item_feature @ W + b ----------
__global__ void k_gemm1(const float* __restrict__ A, const float* __restrict__ W,
                        const float* __restrict__ bias, float* __restrict__ h) {
  __shared__ float arow[D2_DIM];
  const int r = blockIdx.x;
  const int c = threadIdx.x;  // 128
  arow[c] = A[r * D2_DIM + c];
  arow[c + 128] = A[r * D2_DIM + c + 128];
  __syncthreads();
  float acc = 0.f;
#pragma unroll 8
  for (int k = 0; k < D2_DIM; k++) acc = fmaf(arow[k], W[k * D_DIM + c], acc);
  h[r * D_DIM + c] = acc + bias[c];
}

// ---------- kernel 2: per-column mean/var -> scale/shift ----------
__global__ void k_bnstats(const float* __restrict__ h, const float* __restrict__ gamma,
                          const float* __restrict__ beta, float* __restrict__ scale,
                          float* __restrict__ shift) {
  const int c = blockIdx.x;
  const int t = threadIdx.x;  // 256
  double s = 0.0, sq = 0.0;
  for (int r = t; r < B_ROWS; r += 256) {
    double v = (double)h[r * D_DIM + c];
    s += v; sq += v * v;
  }
  __shared__ double ls[256], lq[256];
  ls[t] = s; lq[t] = sq;
  __syncthreads();
  for (int off = 128; off; off >>= 1) {
    if (t < off) { ls[t] += ls[t + off]; lq[t] += lq[t + off]; }
    __syncthreads();
  }
  if (t == 0) {
    double mean = ls[0] / (double)B_ROWS;
    double var = lq[0] / (double)B_ROWS - mean * mean;
    float sc = (float)((double)gamma[c] / sqrt(var + (double)BN_EPS_F));
    scale[c] = sc;
    shift[c] = beta[c] - (float)mean * sc;
  }
}

// ---------- kernel 3: uf = leaky(bn(h)) -> bf16 hi/lo planes ----------
__global__ void k_norm_split(const float* __restrict__ h, const float* __restrict__ scale,
                             const float* __restrict__ shift) {
  int i = blockIdx.x * 256 + threadIdx.x;
  if (i >= B_ROWS * D_DIM) return;
  int c = i & (D_DIM - 1);
  float v = fmaf(h[i], scale[c], shift[c]);
  v = v >= 0.f ? v : LEAKY_F * v;
  unsigned short hi, lo;
  split_bf16(v, hi, lo);
  g_Aph[i] = hi; g_Apl[i] = lo;
}

// ---------- kernel 4: all_items -> bf16 hi/lo planes (pad rows zeroed) ----------
__global__ void k_build_items(const float* __restrict__ items) {
  long long t = (long long)blockIdx.x * 256 + threadIdx.x;
  long long base = t * 4;
  if (base >= (long long)M_PAD * D_DIM) return;
  float4 v;
  if (base < (long long)M_ITEMS * D_DIM) v = *(const float4*)&items[base];
  else v = make_float4(0.f, 0.f, 0.f, 0.f);
  ushort4 hv, lv;
  split_bf16(v.x, hv.x, lv.x);
  split_bf16(v.y, hv.y, lv.y);
  split_bf16(v.z, hv.z, lv.z);
  split_bf16(v.w, hv.w, lv.w);
  *(ushort4*)&g_Bph[base] = hv;
  *(ushort4*)&g_Bpl[base] = lv;
}

// ---------- kernel 5: init argmax keys ----------
__global__ void k_init(unsigned long long* __restrict__ keys) {
  int i = blockIdx.x * blockDim.x + threadIdx.x;
  if (i < B_ROWS) keys[i] = 0ull;
}

// ---------- kernel 6: MFMA scores + fused argmax, ZERO-SYNC ----------
// R14-R18 synthesis: MfmaUtil pinned at ~30% across occupancies/layouts/
// orderings; the invariant was the per-K-step barrier+vmcnt rendezvous.
// This version removes ALL synchronization: no LDS, no barriers. B is
// L2-resident (51MB, row-fast grid keeps concurrent blocks on one chunk);
// each wave loads B fragments straight to registers (4x16B per kf) and the
// compiler pipelines the fully-unrolled loop. 4 waves/SIMD TLP hides L2
// latency. Waves independent: wave w owns rows rowbase+w*32; all 4 waves
// share the same item stripes (L1 serves intra-CU redundancy).
// Regs: A hi+lo 64 + B transients 16 + fold ~20 ~ 105 arch + acc 16 AGPR
// -> launch_bounds(256,4) = 4 waves/SIMD, no spill.
__global__ void __launch_bounds__(256, 4)
k_scores_mfma(unsigned long long* __restrict__ keys) {
  const int tid = threadIdx.x;
  const int l = tid & 63;
  const int w = tid >> 6;      // wave 0..3 -> row group
  const int rowbase = blockIdx.x * BROWS;        // row-block FAST -> B locality
  const int chunk = blockIdx.y * CHUNK;          // item chunk slow
  const int lrow = l & 15;
  const int lkg = l >> 4;      // 0..3
  const bool fullchunk = (chunk + CHUNK) <= M_ITEMS;  // block-uniform

  // ---- A hi+lo -> persistent regs (32 rows per wave) ----
  bf16x8 ah[2][4], al[2][4];
  const int ar = rowbase + w * 32 + lrow;
#pragma unroll
  for (int mi = 0; mi < 2; mi++)
#pragma unroll
    for (int kf = 0; kf < 4; kf++) {
      const size_t off = (size_t)(ar + mi * 16) * D_DIM + kf * 32 + lkg * 8;
      ah[mi][kf] = *(const bf16x8*)&g_Aph[off];
      al[mi][kf] = *(const bf16x8*)&g_Apl[off];
    }

  // per-lane B byte base: item (chunk + lrow), k-quad lkg
  const char* gBh = (const char*)g_Bph;
  const char* gBl = (const char*)g_Bpl;
  const size_t bbase = (size_t)(chunk + lrow) * 256 + lkg * 16;

  // deferred-selection argmax: bestv[mi][reg] + 5-bit (s*2+ni) codes
  float bestv[2][4];
  unsigned sel0 = 0u, sel1 = 0u;   // mi=0 / mi=1, 4 regs x 5 bits each
#pragma unroll
  for (int mi = 0; mi < 2; mi++)
#pragma unroll
    for (int reg = 0; reg < 4; reg++) bestv[mi][reg] = -3.0e38f;

  f32x4 acc[2][2];
#pragma unroll
  for (int mi = 0; mi < 2; mi++)
#pragma unroll
    for (int ni = 0; ni < 2; ni++) acc[mi][ni] = (f32x4)(0.0f);

#pragma unroll
  for (int s = 0; s < CHUNK / 32; s++) {   // 16 stripes of 32 items
#pragma unroll
    for (int kf = 0; kf < 4; kf++) {
      const size_t so = bbase + (size_t)s * 32 * 256 + (size_t)kf * 64;
      bf16x8 bh0 = *(const bf16x8*)(gBh + so);
      bf16x8 bh1 = *(const bf16x8*)(gBh + so + 16 * 256);
      bf16x8 bl0 = *(const bf16x8*)(gBl + so);
      bf16x8 bl1 = *(const bf16x8*)(gBl + so + 16 * 256);
      acc[0][0] = __builtin_amdgcn_mfma_f32_16x16x32_bf16(ah[0][kf], bh0, acc[0][0], 0, 0, 0);
      acc[0][1] = __builtin_amdgcn_mfma_f32_16x16x32_bf16(ah[0][kf], bh1, acc[0][1], 0, 0, 0);
      acc[1][0] = __builtin_amdgcn_mfma_f32_16x16x32_bf16(ah[1][kf], bh0, acc[1][0], 0, 0, 0);
      acc[1][1] = __builtin_amdgcn_mfma_f32_16x16x32_bf16(ah[1][kf], bh1, acc[1][1], 0, 0, 0);
      acc[0][0] = __builtin_amdgcn_mfma_f32_16x16x32_bf16(al[0][kf], bh0, acc[0][0], 0, 0, 0);
      acc[0][1] = __builtin_amdgcn_mfma_f32_16x16x32_bf16(al[0][kf], bh1, acc[0][1], 0, 0, 0);
      acc[1][0] = __builtin_amdgcn_mfma_f32_16x16x32_bf16(al[1][kf], bh0, acc[1][0], 0, 0, 0);
      acc[1][1] = __builtin_amdgcn_mfma_f32_16x16x32_bf16(al[1][kf], bh1, acc[1][1], 0, 0, 0);
      acc[0][0] = __builtin_amdgcn_mfma_f32_16x16x32_bf16(ah[0][kf], bl0, acc[0][0], 0, 0, 0);
      acc[0][1] = __builtin_amdgcn_mfma_f32_16x16x32_bf16(ah[0][kf], bl1, acc[0][1], 0, 0, 0);
      acc[1][0] = __builtin_amdgcn_mfma_f32_16x16x32_bf16(ah[1][kf], bl0, acc[1][0], 0, 0, 0);
      acc[1][1] = __builtin_amdgcn_mfma_f32_16x16x32_bf16(ah[1][kf], bl1, acc[1][1], 0, 0, 0);
    }
    // fold stripe into running best (in-lane; no shuffles)
#pragma unroll
    for (int mi = 0; mi < 2; mi++) {
#pragma unroll
      for (int reg = 0; reg < 4; reg++) {
        float bv = bestv[mi][reg];
        unsigned sl = mi == 0 ? sel0 : sel1;
#pragma unroll
        for (int ni = 0; ni < 2; ni++) {
          const float x = acc[mi][ni][reg];
          bool win;
          if (fullchunk) {
            win = x > bv;
          } else {
            const int col = chunk + s * 32 + ni * 16 + lrow;
            win = (col < M_ITEMS) && (x > bv);
          }
          bv = win ? x : bv;
          const unsigned code = (unsigned)(s * 2 + ni);
          const unsigned sh = reg * 5;
          const unsigned nw = (sl & ~(0x1Fu << sh)) | (code << sh);
          sl = win ? nw : sl;
        }
        bestv[mi][reg] = bv;
        if (mi == 0) sel0 = sl; else sel1 = sl;
      }
#pragma unroll
      for (int ni = 0; ni < 2; ni++) acc[mi][ni] = (f32x4)(0.0f);
    }
  }

  // final fold: one butterfly per q=(mi,reg); owner lane lrow==q keeps key
  unsigned long long rb = 0ull;
#pragma unroll
  for (int mi = 0; mi < 2; mi++) {
#pragma unroll
    for (int reg = 0; reg < 4; reg++) {
      const int q = mi * 4 + reg;
      const unsigned code = ((mi == 0 ? sel0 : sel1) >> (reg * 5)) & 0x1Fu;
      float v = bestv[mi][reg];
      int bi = chunk + (int)code * 16 + lrow;
#pragma unroll
      for (int off = 1; off < 16; off <<= 1) {
        float ov = __shfl_xor(v, off, 16);
        int oi = __shfl_xor(bi, off, 16);
        if (ov > v || (ov == v && oi < bi)) { v = ov; bi = oi; }
      }
      if (lrow == q) rb = pack_key(v, bi);
    }
  }
  // lanes lrow<8 each own one distinct row of the wave's 32
  if (lrow < 8) {
    const int myrow = rowbase + w * 32 + (lrow >> 2) * 16 + lkg * 4 + (lrow & 3);
    atomicMax(&keys[myrow], rb);
  }
}

// ---------- kernel 7: unpack top1, gather, cosine sim ----------
__global__ void k_post(const unsigned long long* __restrict__ keys,
                       const int* __restrict__ uid,
                       const float* __restrict__ items,
                       float* __restrict__ out, float* __restrict__ sims,
                       float* __restrict__ rl) {
  int r = blockIdx.x * blockDim.x + threadIdx.x;
  if (r >= B_ROWS) return;
  unsigned long long key = keys[r];
  int idx = (int)(~(unsigned)(key & 0xFFFFFFFFull));
  out[r] = (float)idx;
  int orig = uid[2 * r + 1];
  const float* a = items + (long long)orig * D_DIM;
  const float* c = items + (long long)idx * D_DIM;
  float aa = 0.f, cc = 0.f, ac = 0.f;
#pragma unroll 4
  for (int d = 0; d < D_DIM; d++) {
    float x = a[d], y = c[d];
    aa = fmaf(x, x, aa);
    cc = fmaf(y, y, cc);
    ac = fmaf(x, y, ac);
  }
  float na = fmaxf(sqrtf(aa), COS_EPS_F);
  float nc = fmaxf(sqrtf(cc), COS_EPS_F);
  float sim = ac / (na * nc);
  sim = (sim + 1.f) * 0.5f;
  sims[r] = sim;
  rl[r] = fmaxf(sim - 0.5f, 0.f);
}

// ---------- kernel 8: deterministic final means ----------
__global__ void k_final(const float* __restrict__ sims, const float* __restrict__ rl,
                        float* __restrict__ out) {
  __shared__ float s1[256], s2[256];
  int t = threadIdx.x;
  float a = 0.f, b = 0.f;
  for (int r = t; r < B_ROWS; r += 256) { a += rl[r]; b += sims[r]; }
  s1[t] = a; s2[t] = b;
  __syncthreads();
  for (int off = 128; off; off >>= 1) {
    if (t < off) { s1[t] += s1[t + off]; s2[t] += s2[t + off]; }
    __syncthreads();
  }
  if (t == 0) {
    out[B_ROWS] = s1[0] / (float)B_ROWS;
    out[B_ROWS + 1] = s2[0] / (float)B_ROWS;
  }
}

extern "C" void kernel_launch(void* const* d_in, const int* in_sizes, int n_in,
                              void* d_out, int out_size, void* d_ws, size_t ws_size,
                              hipStream_t stream) {
  const float* item_feature = (const float*)d_in[0];
  const float* all_items    = (const float*)d_in[1];
  const int*   uid          = (const int*)d_in[2];
  const float* W            = (const float*)d_in[3];
  const float* bias         = (const float*)d_in[4];
  const float* gamma        = (const float*)d_in[5];
  const float* beta         = (const float*)d_in[6];
  float* out = (float*)d_out;

  float* h     = (float*)d_ws;             // 2048*128
  float* scale = h + B_ROWS * D_DIM;       // 128
  float* shift = scale + D_DIM;            // 128
  unsigned long long* keys = (unsigned long long*)(shift + D_DIM);  // 2048
  float* sims  = (float*)(keys + B_ROWS);  // 2048
  float* rl    = sims + B_ROWS;            // 2048

  k_gemm1<<<B_ROWS, D_DIM, 0, stream>>>(item_feature, W, bias, h);
  k_bnstats<<<D_DIM, 256, 0, stream>>>(h, gamma, beta, scale, shift);
  k_norm_split<<<(B_ROWS * D_DIM + 255) / 256, 256, 0, stream>>>(h, scale, shift);
  k_build_items<<<(M_PAD * D_DIM / 4 + 255) / 256, 256, 0, stream>>>(all_items);
  k_init<<<(B_ROWS + 255) / 256, 256, 0, stream>>>(keys);
  dim3 sg(B_ROWS / BROWS, M_PAD / CHUNK);   // x = row-block (fast), y = item chunk
  k_scores_mfma<<<sg, 256, 0, stream>>>(keys);
  k_post<<<(B_ROWS + 255) / 256, 256, 0, stream>>>(keys, uid, all_items, out, sims, rl);
  k_final<<<1, 256, 0, stream>>>(sims, rl, out);
}

// Round 20
// 263.686 us; speedup vs baseline: 1.8150x; 1.8150x over previous
//
#include <hip/hip_runtime.h>
#include <stdint.h>

#define B_ROWS 2048
#define D2_DIM 256
#define D_DIM 128
#define M_ITEMS 100000
#define M_PAD 100352           // 196 * 512
#define BN_EPS_F 1e-5f
#define COS_EPS_F 1e-6f
#define LEAKY_F 0.01f

#define BNI 128                // items per tile
#define BK 32                  // K per stage
#define SUPER 4                // item tiles per block -> 512 items/block

typedef __bf16 bf16x8 __attribute__((ext_vector_type(8)));
typedef float f32x4 __attribute__((ext_vector_type(4)));

// bf16 hi/lo split planes (device globals; rebuilt every call)
__device__ unsigned short g_Aph[B_ROWS * D_DIM];
__device__ unsigned short g_Apl[B_ROWS * D_DIM];
__device__ unsigned short g_Bph[M_PAD * D_DIM];
__device__ unsigned short g_Bpl[M_PAD * D_DIM];

__device__ __forceinline__ unsigned bf16_rne(float f) {
  unsigned u = __float_as_uint(f);
  return (u + 0x7fffu + ((u >> 16) & 1u)) >> 16;
}
__device__ __forceinline__ void split_bf16(float v, unsigned short& hi, unsigned short& lo) {
  unsigned h = bf16_rne(v);
  float hf = __uint_as_float(h << 16);
  unsigned l = bf16_rne(v - hf);   // exact residual
  hi = (unsigned short)h; lo = (unsigned short)l;
}
__device__ __forceinline__ void gload16(const void* g, void* l) {
  __builtin_amdgcn_global_load_lds(
      (const __attribute__((address_space(1))) void*)g,
      (__attribute__((address_space(3))) void*)l, 16, 0, 0);
}
__device__ __forceinline__ unsigned long long pack_key(float v, int idx) {
  unsigned u = __float_as_uint(v);
  u = (u & 0x80000000u) ? ~u : (u | 0x80000000u);
  return ((unsigned long long)u << 32) | (unsigned)(~(unsigned)idx);
}

// ---------- kernel 1: h = item_feature @ W + b ----------
__global__ void k_gemm1(const float* __restrict__ A, const float* __restrict__ W,
                        const float* __restrict__ bias, float* __restrict__ h) {
  __shared__ float arow[D2_DIM];
  const int r = blockIdx.x;
  const int c = threadIdx.x;  // 128
  arow[c] = A[r * D2_DIM + c];
  arow[c + 128] = A[r * D2_DIM + c + 128];
  __syncthreads();
  float acc = 0.f;
#pragma unroll 8
  for (int k = 0; k < D2_DIM; k++) acc = fmaf(arow[k], W[k * D_DIM + c], acc);
  h[r * D_DIM + c] = acc + bias[c];
}

// ---------- kernel 2: per-column mean/var -> scale/shift ----------
__global__ void k_bnstats(const float* __restrict__ h, const float* __restrict__ gamma,
                          const float* __restrict__ beta, float* __restrict__ scale,
                          float* __restrict__ shift) {
  const int c = blockIdx.x;
  const int t = threadIdx.x;  // 256
  double s = 0.0, sq = 0.0;
  for (int r = t; r < B_ROWS; r += 256) {
    double v = (double)h[r * D_DIM + c];
    s += v; sq += v * v;
  }
  __shared__ double ls[256], lq[256];
  ls[t] = s; lq[t] = sq;
  __syncthreads();
  for (int off = 128; off; off >>= 1) {
    if (t < off) { ls[t] += ls[t + off]; lq[t] += lq[t + off]; }
    __syncthreads();
  }
  if (t == 0) {
    double mean = ls[0] / (double)B_ROWS;
    double var = lq[0] / (double)B_ROWS - mean * mean;
    float sc = (float)((double)gamma[c] / sqrt(var + (double)BN_EPS_F));
    scale[c] = sc;
    shift[c] = beta[c] - (float)mean * sc;
  }
}

// ---------- kernel 3: uf = leaky(bn(h)) -> bf16 hi/lo planes ----------
__global__ void k_norm_split(const float* __restrict__ h, const float* __restrict__ scale,
                             const float* __restrict__ shift) {
  int i = blockIdx.x * 256 + threadIdx.x;
  if (i >= B_ROWS * D_DIM) return;
  int c = i & (D_DIM - 1);
  float v = fmaf(h[i], scale[c], shift[c]);
  v = v >= 0.f ? v : LEAKY_F * v;
  unsigned short hi, lo;
  split_bf16(v, hi, lo);
  g_Aph[i] = hi; g_Apl[i] = lo;
}

// ---------- kernel 4: all_items -> bf16 hi/lo planes; also zero argmax keys ----------
__global__ void k_build_items(const float* __restrict__ items,
                              unsigned long long* __restrict__ keys) {
  long long t = (long long)blockIdx.x * 256 + threadIdx.x;
  if (t < B_ROWS) keys[t] = 0ull;     // fused k_init (same-stream ordering)
  long long base = t * 4;
  if (base >= (long long)M_PAD * D_DIM) return;
  float4 v;
  if (base < (long long)M_ITEMS * D_DIM) v = *(const float4*)&items[base];
  else v = make_float4(0.f, 0.f, 0.f, 0.f);
  ushort4 hv, lv;
  split_bf16(v.x, hv.x, lv.x);
  split_bf16(v.y, hv.y, lv.y);
  split_bf16(v.z, hv.z, lv.z);
  split_bf16(v.w, hv.w, lv.w);
  *(ushort4*)&g_Bph[base] = hv;
  *(ushort4*)&g_Bpl[base] = lv;
}

// ---------- kernel 6: MFMA scores + fused argmax ----------
// R17 (best: 226us k_scores, 264.9us total). The only non-spilling register
// layout found in R8-R19: acc in AGPR, bestv AGPR-pinned via
// v_accvgpr_write, ah + transients in arch VGPRs, A-lo in LDS. B 3-deep
// 16KB ring, counted vmcnt(4), 2-ahead prefetch, both-sides 0-conflict
// swizzles, 80KB LDS -> 2 blocks/CU. Deferred-selection argmax (in-lane
// fold + one butterfly per block). Term-major MFMA passes.
// R18 (4 waves/SIMD) and R19 (zero-sync, no LDS) both regressed; this
// structure is the measured local optimum.
__global__
__attribute__((amdgpu_flat_work_group_size(256, 256), amdgpu_waves_per_eu(2, 2)))
void k_scores_mfma(unsigned long long* __restrict__ keys) {
  __shared__ __align__(16) char smem[81920];   // 3x16KB B ring + 32KB A-lo
  char* sAlo = smem + 49152;

  const int tid = threadIdx.x;
  const int l = tid & 63;
  const int w = tid >> 6;      // 0..3
  const int wm = w >> 1;       // row half
  const int wn = w & 1;        // item half
  const int rowbase = blockIdx.x * 128;          // row-block FAST -> B locality
  const int chunk = blockIdx.y * (SUPER * BNI);  // item chunk slow
  const int lrow = l & 15;
  const int lkg = l >> 4;      // 0..3
  const bool fullchunk = (chunk + SUPER * BNI) <= M_ITEMS;  // block-uniform

  // per-thread constant staging offsets
  int tb0, tb1, ldst;
  {
    const int s0 = tid;
    const int s1 = tid + 256;
    tb0 = (s0 >> 2) * 256 + (((s0 & 3) ^ ((s0 >> 3) & 3)) * 16);
    tb1 = (s1 >> 2) * 256 + (((s1 & 3) ^ ((s1 >> 3) & 3)) * 16);
    ldst = tid * 16;           // LDS dest (linear), +4096 for rep 1
  }
  const char* gBh = (const char*)g_Bph;
  const char* gBl = (const char*)g_Bpl;

  // ---- B stage (hi 8KB @ buf, lo 8KB @ buf+8192), source pre-swizzled ----
  auto STAGEB = [&](int itembase, int ks, char* buf) {
    const size_t ub = (size_t)itembase * 256 + (size_t)ks * 2;
    gload16(gBh + ub + tb0, buf + ldst);
    gload16(gBl + ub + tb0, buf + 8192 + ldst);
    gload16(gBh + ub + tb1, buf + ldst + 4096);
    gload16(gBl + ub + tb1, buf + 8192 + ldst + 4096);
  };

  // ---- prologue ----
  // A-lo -> LDS: slot s (row=s>>4, sig=s&15) holds k-quad sig^(row&15)
#pragma unroll
  for (int rep = 0; rep < 8; rep++) {
    const int s = tid + rep * 256;        // 2048 slots
    gload16(g_Apl + (size_t)(rowbase + (s >> 4)) * D_DIM
                  + ((s & 15) ^ ((s >> 4) & 15)) * 8,
            sAlo + s * 16);
  }
  STAGEB(chunk, 0, smem);          // stage 0
  STAGEB(chunk, BK, smem + 16384); // stage 1

  bf16x8 ah[4][4];
  const int ar = rowbase + wm * 64 + lrow;
#pragma unroll
  for (int mi = 0; mi < 4; mi++)
#pragma unroll
    for (int kf = 0; kf < 4; kf++)
      ah[mi][kf] = *(const bf16x8*)&g_Aph[(size_t)(ar + mi * 16) * D_DIM + kf * 32 + lkg * 8];

  // ds_read base for B: imm covers buf*16384 + plane*8192 + ni*1024
  char* lbase = smem + wn * 4096 + lrow * 64 + ((lkg ^ ((lrow >> 1) & 3)) << 4);

  // deferred-selection argmax state; bestv pinned to AGPRs via asm defs
  float bestv[4][4];
  unsigned sel0 = 0u, sel1 = 0u;   // 16 x 4-bit (s*4+ni) codes
#pragma unroll
  for (int mi = 0; mi < 4; mi++)
#pragma unroll
    for (int reg = 0; reg < 4; reg++)
      asm volatile("v_accvgpr_write_b32 %0, %1"
                   : "=a"(bestv[mi][reg]) : "v"(-3.0e38f));

  f32x4 acc[4][4];
#pragma unroll
  for (int mi = 0; mi < 4; mi++)
#pragma unroll
    for (int ni = 0; ni < 4; ni++) acc[mi][ni] = (f32x4)(0.0f);

#pragma unroll
  for (int s = 0; s < SUPER; s++) {
    const int itembase = chunk + s * BNI;
#pragma unroll
    for (int kf = 0; kf < 4; kf++) {
      const int j = s * 4 + kf;
      // own stage-j landed (stage j+1 stays in flight)
      asm volatile("s_waitcnt vmcnt(4)" ::: "memory");
      __builtin_amdgcn_s_barrier();   // all waves' stage-j landed; buf[(j+2)%3] free
      {
        const int q = j + 2;          // prefetch 2 steps ahead (tail: dummy reload)
        const int qt = (q >> 2) & (SUPER - 1);
        STAGEB(chunk + qt * BNI, (q & 3) * BK, smem + (q % 3) * 16384);
      }
      const int jb = (j % 3) * 16384;   // compile-time (loop fully unrolled)
      bf16x8 bh[4], bl[4], alo[4];
#pragma unroll
      for (int ni = 0; ni < 4; ni++) {
        bh[ni] = *(const bf16x8*)(lbase + jb + ni * 1024);
        bl[ni] = *(const bf16x8*)(lbase + jb + 8192 + ni * 1024);
      }
#pragma unroll
      for (int mi = 0; mi < 4; mi++) {
        const int row = wm * 64 + mi * 16 + lrow;
        const int off = row * 256 + (((kf * 4 + lkg) ^ (row & 15)) << 4);
        alo[mi] = *(const bf16x8*)(sAlo + off);
      }
      __builtin_amdgcn_s_setprio(1);
      // term-major: three passes of 16 independent MFMAs
#pragma unroll
      for (int mi = 0; mi < 4; mi++)
#pragma unroll
        for (int ni = 0; ni < 4; ni++)
          acc[mi][ni] = __builtin_amdgcn_mfma_f32_16x16x32_bf16(
              ah[mi][kf], bh[ni], acc[mi][ni], 0, 0, 0);
#pragma unroll
      for (int mi = 0; mi < 4; mi++)
#pragma unroll
        for (int ni = 0; ni < 4; ni++)
          acc[mi][ni] = __builtin_amdgcn_mfma_f32_16x16x32_bf16(
              alo[mi], bh[ni], acc[mi][ni], 0, 0, 0);
#pragma unroll
      for (int mi = 0; mi < 4; mi++)
#pragma unroll
        for (int ni = 0; ni < 4; ni++)
          acc[mi][ni] = __builtin_amdgcn_mfma_f32_16x16x32_bf16(
              ah[mi][kf], bl[ni], acc[mi][ni], 0, 0, 0);
      __builtin_amdgcn_s_setprio(0);
    }
    if (fullchunk) {
      // fast fold: tile-max + branchless ni recovery (ties -> lowest ni ->
      // lowest col; strict > across tiles keeps earliest s -> lowest col)
#pragma unroll
      for (int mi = 0; mi < 4; mi++) {
#pragma unroll
        for (int reg = 0; reg < 4; reg++) {
          const int q = mi * 4 + reg;
          const float x0 = acc[mi][0][reg], x1 = acc[mi][1][reg];
          const float x2 = acc[mi][2][reg], x3 = acc[mi][3][reg];
          const float tm = fmaxf(fmaxf(fmaxf(x0, x1), x2), x3);
          float bv = bestv[mi][reg];
          const bool win = tm > bv;
          bv = win ? tm : bv;
          const unsigned c = (x0 == tm) ? 0u : (x1 == tm) ? 1u : (x2 == tm) ? 2u : 3u;
          const unsigned code = (unsigned)(s * 4) + c;
          if (q < 8) {
            const unsigned nw = (sel0 & ~(0xFu << (q * 4))) | (code << (q * 4));
            sel0 = win ? nw : sel0;
          } else {
            const unsigned nw = (sel1 & ~(0xFu << ((q - 8) * 4))) | (code << ((q - 8) * 4));
            sel1 = win ? nw : sel1;
          }
          asm volatile("v_accvgpr_write_b32 %0, %1"
                       : "=a"(bestv[mi][reg]) : "v"(bv));
        }
#pragma unroll
        for (int ni = 0; ni < 4; ni++) acc[mi][ni] = (f32x4)(0.0f);
      }
    } else {
      // guarded fold (pad chunk only): per-candidate path
#pragma unroll
      for (int mi = 0; mi < 4; mi++) {
#pragma unroll
        for (int reg = 0; reg < 4; reg++) {
          const int q = mi * 4 + reg;
          float bv = bestv[mi][reg];
#pragma unroll
          for (int ni = 0; ni < 4; ni++) {
            const float x = acc[mi][ni][reg];
            const int col = itembase + wn * 64 + ni * 16 + lrow;
            const bool win = (col < M_ITEMS) && (x > bv);
            bv = win ? x : bv;
            const unsigned code = (unsigned)(s * 4 + ni);
            if (q < 8) {
              const unsigned nw = (sel0 & ~(0xFu << (q * 4))) | (code << (q * 4));
              sel0 = win ? nw : sel0;
            } else {
              const unsigned nw = (sel1 & ~(0xFu << ((q - 8) * 4))) | (code << ((q - 8) * 4));
              sel1 = win ? nw : sel1;
            }
          }
          asm volatile("v_accvgpr_write_b32 %0, %1"
                       : "=a"(bestv[mi][reg]) : "v"(bv));
        }
#pragma unroll
        for (int ni = 0; ni < 4; ni++) acc[mi][ni] = (f32x4)(0.0f);
      }
    }
  }
  asm volatile("s_waitcnt vmcnt(0)" ::: "memory");  // drain dummy tail prefetches

  // final fold: ONE butterfly per q; owner lane (lrow==q) keeps its row's key
  unsigned long long rb = 0ull;
#pragma unroll
  for (int mi = 0; mi < 4; mi++) {
#pragma unroll
    for (int reg = 0; reg < 4; reg++) {
      const int q = mi * 4 + reg;
      const unsigned code = (q < 8 ? (sel0 >> (q * 4)) : (sel1 >> ((q - 8) * 4))) & 0xFu;
      float v = bestv[mi][reg];
      int bi = chunk + (int)(code >> 2) * BNI + wn * 64 + (int)(code & 3) * 16 + lrow;
#pragma unroll
      for (int off = 1; off < 16; off <<= 1) {
        float ov = __shfl_xor(v, off, 16);
        int oi = __shfl_xor(bi, off, 16);
        if (ov > v || (ov == v && oi < bi)) { v = ov; bi = oi; }
      }
      if (lrow == q) rb = pack_key(v, bi);
    }
  }
  // each lane owns one distinct row of the wave's 64
  const int myrow = rowbase + wm * 64 + (lrow >> 2) * 16 + lkg * 4 + (lrow & 3);
  atomicMax(&keys[myrow], rb);
}

// ---------- kernel 7: unpack top1, gather, cosine sim ----------
__global__ void k_post(const unsigned long long* __restrict__ keys,
                       const int* __restrict__ uid,
                       const float* __restrict__ items,
                       float* __restrict__ out, float* __restrict__ sims,
                       float* __restrict__ rl) {
  int r = blockIdx.x * blockDim.x + threadIdx.x;
  if (r >= B_ROWS) return;
  unsigned long long key = keys[r];
  int idx = (int)(~(unsigned)(key & 0xFFFFFFFFull));
  out[r] = (float)idx;
  int orig = uid[2 * r + 1];
  const float* a = items + (long long)orig * D_DIM;
  const float* c = items + (long long)idx * D_DIM;
  float aa = 0.f, cc = 0.f, ac = 0.f;
#pragma unroll 4
  for (int d = 0; d < D_DIM; d++) {
    float x = a[d], y = c[d];
    aa = fmaf(x, x, aa);
    cc = fmaf(y, y, cc);
    ac = fmaf(x, y, ac);
  }
  float na = fmaxf(sqrtf(aa), COS_EPS_F);
  float nc = fmaxf(sqrtf(cc), COS_EPS_F);
  float sim = ac / (na * nc);
  sim = (sim + 1.f) * 0.5f;
  sims[r] = sim;
  rl[r] = fmaxf(sim - 0.5f, 0.f);
}

// ---------- kernel 8: deterministic final means ----------
__global__ void k_final(const float* __restrict__ sims, const float* __restrict__ rl,
                        float* __restrict__ out) {
  __shared__ float s1[256], s2[256];
  int t = threadIdx.x;
  float a = 0.f, b = 0.f;
  for (int r = t; r < B_ROWS; r += 256) { a += rl[r]; b += sims[r]; }
  s1[t] = a; s2[t] = b;
  __syncthreads();
  for (int off = 128; off; off >>= 1) {
    if (t < off) { s1[t] += s1[t + off]; s2[t] += s2[t + off]; }
    __syncthreads();
  }
  if (t == 0) {
    out[B_ROWS] = s1[0] / (float)B_ROWS;
    out[B_ROWS + 1] = s2[0] / (float)B_ROWS;
  }
}

extern "C" void kernel_launch(void* const* d_in, const int* in_sizes, int n_in,
                              void* d_out, int out_size, void* d_ws, size_t ws_size,
                              hipStream_t stream) {
  const float* item_feature = (const float*)d_in[0];
  const float* all_items    = (const float*)d_in[1];
  const int*   uid          = (const int*)d_in[2];
  const float* W            = (const float*)d_in[3];
  const float* bias         = (const float*)d_in[4];
  const float* gamma        = (const float*)d_in[5];
  const float* beta         = (const float*)d_in[6];
  float* out = (float*)d_out;

  float* h     = (float*)d_ws;             // 2048*128
  float* scale = h + B_ROWS * D_DIM;       // 128
  float* shift = scale + D_DIM;            // 128
  unsigned long long* keys = (unsigned long long*)(shift + D_DIM);  // 2048
  float* sims  = (float*)(keys + B_ROWS);  // 2048
  float* rl    = sims + B_ROWS;            // 2048

  k_gemm1<<<B_ROWS, D_DIM, 0, stream>>>(item_feature, W, bias, h);
  k_bnstats<<<D_DIM, 256, 0, stream>>>(h, gamma, beta, scale, shift);
  k_norm_split<<<(B_ROWS * D_DIM + 255) / 256, 256, 0, stream>>>(h, scale, shift);
  k_build_items<<<(M_PAD * D_DIM / 4 + 255) / 256, 256, 0, stream>>>(all_items, keys);
  dim3 sg(B_ROWS / 128, M_PAD / (SUPER * BNI));   // x = row-block (fast), y = item chunk
  k_scores_mfma<<<sg, 256, 0, stream>>>(keys);
  k_post<<<(B_ROWS + 255) / 256, 256, 0, stream>>>(keys, uid, all_items, out, sims, rl);
  k_final<<<1, 256, 0, stream>>>(sims, rl, out);
}

// Round 21
// 252.351 us; speedup vs baseline: 1.8965x; 1.0449x over previous
//
#include <hip/hip_runtime.h>
#include <stdint.h>

#define B_ROWS 2048
#define D2_DIM 256
#define D_DIM 128
#define M_ITEMS 100000
#define M_PAD 100352           // 196 * 512
#define BN_EPS_F 1e-5f
#define COS_EPS_F 1e-6f
#define LEAKY_F 0.01f

#define BNI 128                // items per tile
#define BK 32                  // K per stage
#define SUPER 4                // item tiles per block -> 512 items/block

typedef __bf16 bf16x8 __attribute__((ext_vector_type(8)));
typedef float f32x4 __attribute__((ext_vector_type(4)));

// bf16 hi/lo split planes (device globals; rebuilt every call)
__device__ unsigned short g_Aph[B_ROWS * D_DIM];
__device__ unsigned short g_Apl[B_ROWS * D_DIM];
__device__ unsigned short g_Bph[M_PAD * D_DIM];
__device__ unsigned short g_Bpl[M_PAD * D_DIM];

__device__ __forceinline__ unsigned bf16_rne(float f) {
  unsigned u = __float_as_uint(f);
  return (u + 0x7fffu + ((u >> 16) & 1u)) >> 16;
}
__device__ __forceinline__ void split_bf16(float v, unsigned short& hi, unsigned short& lo) {
  unsigned h = bf16_rne(v);
  float hf = __uint_as_float(h << 16);
  unsigned l = bf16_rne(v - hf);   // exact residual
  hi = (unsigned short)h; lo = (unsigned short)l;
}
__device__ __forceinline__ void gload16(const void* g, void* l) {
  __builtin_amdgcn_global_load_lds(
      (const __attribute__((address_space(1))) void*)g,
      (__attribute__((address_space(3))) void*)l, 16, 0, 0);
}
__device__ __forceinline__ unsigned long long pack_key(float v, int idx) {
  unsigned u = __float_as_uint(v);
  u = (u & 0x80000000u) ? ~u : (u | 0x80000000u);
  return ((unsigned long long)u << 32) | (unsigned)(~(unsigned)idx);
}

// ---------- kernel 1: h = item_feature @ W + b ----------
__global__ void k_gemm1(const float* __restrict__ A, const float* __restrict__ W,
                        const float* __restrict__ bias, float* __restrict__ h) {
  __shared__ float arow[D2_DIM];
  const int r = blockIdx.x;
  const int c = threadIdx.x;  // 128
  arow[c] = A[r * D2_DIM + c];
  arow[c + 128] = A[r * D2_DIM + c + 128];
  __syncthreads();
  float acc = 0.f;
#pragma unroll 8
  for (int k = 0; k < D2_DIM; k++) acc = fmaf(arow[k], W[k * D_DIM + c], acc);
  h[r * D_DIM + c] = acc + bias[c];
}

// ---------- kernel 2: per-column mean/var -> scale/shift ----------
__global__ void k_bnstats(const float* __restrict__ h, const float* __restrict__ gamma,
                          const float* __restrict__ beta, float* __restrict__ scale,
                          float* __restrict__ shift) {
  const int c = blockIdx.x;
  const int t = threadIdx.x;  // 256
  double s = 0.0, sq = 0.0;
  for (int r = t; r < B_ROWS; r += 256) {
    double v = (double)h[r * D_DIM + c];
    s += v; sq += v * v;
  }
  __shared__ double ls[256], lq[256];
  ls[t] = s; lq[t] = sq;
  __syncthreads();
  for (int off = 128; off; off >>= 1) {
    if (t < off) { ls[t] += ls[t + off]; lq[t] += lq[t + off]; }
    __syncthreads();
  }
  if (t == 0) {
    double mean = ls[0] / (double)B_ROWS;
    double var = lq[0] / (double)B_ROWS - mean * mean;
    float sc = (float)((double)gamma[c] / sqrt(var + (double)BN_EPS_F));
    scale[c] = sc;
    shift[c] = beta[c] - (float)mean * sc;
  }
}

// ---------- kernel 3: uf = leaky(bn(h)) -> bf16 hi/lo planes ----------
__global__ void k_norm_split(const float* __restrict__ h, const float* __restrict__ scale,
                             const float* __restrict__ shift) {
  int i = blockIdx.x * 256 + threadIdx.x;
  if (i >= B_ROWS * D_DIM) return;
  int c = i & (D_DIM - 1);
  float v = fmaf(h[i], scale[c], shift[c]);
  v = v >= 0.f ? v : LEAKY_F * v;
  unsigned short hi, lo;
  split_bf16(v, hi, lo);
  g_Aph[i] = hi; g_Apl[i] = lo;
}

// ---------- kernel 4: all_items -> bf16 hi/lo planes; also zero argmax keys ----------
__global__ void k_build_items(const float* __restrict__ items,
                              unsigned long long* __restrict__ keys) {
  long long t = (long long)blockIdx.x * 256 + threadIdx.x;
  if (t < B_ROWS) keys[t] = 0ull;     // fused k_init (same-stream ordering)
  long long base = t * 4;
  if (base >= (long long)M_PAD * D_DIM) return;
  float4 v;
  if (base < (long long)M_ITEMS * D_DIM) v = *(const float4*)&items[base];
  else v = make_float4(0.f, 0.f, 0.f, 0.f);
  ushort4 hv, lv;
  split_bf16(v.x, hv.x, lv.x);
  split_bf16(v.y, hv.y, lv.y);
  split_bf16(v.z, hv.z, lv.z);
  split_bf16(v.w, hv.w, lv.w);
  *(ushort4*)&g_Bph[base] = hv;
  *(ushort4*)&g_Bpl[base] = lv;
}

// ---------- kernel 6: MFMA scores + fused argmax ----------
// R20 body (best: 224us k_scores) + XCD-locality block swizzle (T1).
// R20 counters: FETCH_SIZE 277MB vs 53MB unique working set at ~1.5TB/s
// fabric = 186us ~ 83% of runtime -> L2-fill-bound. Cause: the 16 row-
// blocks sharing an item chunk were consecutive linear ids -> round-robined
// across all 8 XCDs, so every chunk filled ~5-8 per-XCD L2s. Fix: 1D grid
// + bijective remap so all 16 row-blocks of a chunk-group land on ONE XCD
// (assignment = id%8): chunk fetched into exactly one L2.
__global__
__attribute__((amdgpu_flat_work_group_size(256, 256), amdgpu_waves_per_eu(2, 2)))
void k_scores_mfma(unsigned long long* __restrict__ keys) {
  __shared__ __align__(16) char smem[81920];   // 3x16KB B ring + 32KB A-lo
  char* sAlo = smem + 49152;

  const int tid = threadIdx.x;
  const int l = tid & 63;
  const int w = tid >> 6;      // 0..3
  const int wm = w >> 1;       // row half
  const int wn = w & 1;        // item half

  // ---- XCD-locality swizzle: group G (chunk) pinned to XCD G%8 ----
  int G, xrb;
  {
    const int n = blockIdx.x;          // 0..3135
    const int xcd = n & 7, j = n >> 3; // j: 0..391 within XCD
    if (j < 384) { G = (j >> 4) * 8 + xcd; xrb = j & 15; }
    else { const int o = xcd * 8 + (j - 384); G = 192 + (o >> 4); xrb = o & 15; }
  }
  const int rowbase = xrb * 128;
  const int chunk = G * (SUPER * BNI);
  const int lrow = l & 15;
  const int lkg = l >> 4;      // 0..3
  const bool fullchunk = (chunk + SUPER * BNI) <= M_ITEMS;  // block-uniform

  // per-thread constant staging offsets
  int tb0, tb1, ldst;
  {
    const int s0 = tid;
    const int s1 = tid + 256;
    tb0 = (s0 >> 2) * 256 + (((s0 & 3) ^ ((s0 >> 3) & 3)) * 16);
    tb1 = (s1 >> 2) * 256 + (((s1 & 3) ^ ((s1 >> 3) & 3)) * 16);
    ldst = tid * 16;           // LDS dest (linear), +4096 for rep 1
  }
  const char* gBh = (const char*)g_Bph;
  const char* gBl = (const char*)g_Bpl;

  // ---- B stage (hi 8KB @ buf, lo 8KB @ buf+8192), source pre-swizzled ----
  auto STAGEB = [&](int itembase, int ks, char* buf) {
    const size_t ub = (size_t)itembase * 256 + (size_t)ks * 2;
    gload16(gBh + ub + tb0, buf + ldst);
    gload16(gBl + ub + tb0, buf + 8192 + ldst);
    gload16(gBh + ub + tb1, buf + ldst + 4096);
    gload16(gBl + ub + tb1, buf + 8192 + ldst + 4096);
  };

  // ---- prologue ----
  // A-lo -> LDS: slot s (row=s>>4, sig=s&15) holds k-quad sig^(row&15)
#pragma unroll
  for (int rep = 0; rep < 8; rep++) {
    const int s = tid + rep * 256;        // 2048 slots
    gload16(g_Apl + (size_t)(rowbase + (s >> 4)) * D_DIM
                  + ((s & 15) ^ ((s >> 4) & 15)) * 8,
            sAlo + s * 16);
  }
  STAGEB(chunk, 0, smem);          // stage 0
  STAGEB(chunk, BK, smem + 16384); // stage 1

  bf16x8 ah[4][4];
  const int ar = rowbase + wm * 64 + lrow;
#pragma unroll
  for (int mi = 0; mi < 4; mi++)
#pragma unroll
    for (int kf = 0; kf < 4; kf++)
      ah[mi][kf] = *(const bf16x8*)&g_Aph[(size_t)(ar + mi * 16) * D_DIM + kf * 32 + lkg * 8];

  // ds_read base for B: imm covers buf*16384 + plane*8192 + ni*1024
  char* lbase = smem + wn * 4096 + lrow * 64 + ((lkg ^ ((lrow >> 1) & 3)) << 4);

  // deferred-selection argmax state; bestv pinned to AGPRs via asm defs
  float bestv[4][4];
  unsigned sel0 = 0u, sel1 = 0u;   // 16 x 4-bit (s*4+ni) codes
#pragma unroll
  for (int mi = 0; mi < 4; mi++)
#pragma unroll
    for (int reg = 0; reg < 4; reg++)
      asm volatile("v_accvgpr_write_b32 %0, %1"
                   : "=a"(bestv[mi][reg]) : "v"(-3.0e38f));

  f32x4 acc[4][4];
#pragma unroll
  for (int mi = 0; mi < 4; mi++)
#pragma unroll
    for (int ni = 0; ni < 4; ni++) acc[mi][ni] = (f32x4)(0.0f);

#pragma unroll
  for (int s = 0; s < SUPER; s++) {
    const int itembase = chunk + s * BNI;
#pragma unroll
    for (int kf = 0; kf < 4; kf++) {
      const int j = s * 4 + kf;
      // own stage-j landed (stage j+1 stays in flight)
      asm volatile("s_waitcnt vmcnt(4)" ::: "memory");
      __builtin_amdgcn_s_barrier();   // all waves' stage-j landed; buf[(j+2)%3] free
      {
        const int q = j + 2;          // prefetch 2 steps ahead (tail: dummy reload)
        const int qt = (q >> 2) & (SUPER - 1);
        STAGEB(chunk + qt * BNI, (q & 3) * BK, smem + (q % 3) * 16384);
      }
      const int jb = (j % 3) * 16384;   // compile-time (loop fully unrolled)
      bf16x8 bh[4], bl[4], alo[4];
#pragma unroll
      for (int ni = 0; ni < 4; ni++) {
        bh[ni] = *(const bf16x8*)(lbase + jb + ni * 1024);
        bl[ni] = *(const bf16x8*)(lbase + jb + 8192 + ni * 1024);
      }
#pragma unroll
      for (int mi = 0; mi < 4; mi++) {
        const int row = wm * 64 + mi * 16 + lrow;
        const int off = row * 256 + (((kf * 4 + lkg) ^ (row & 15)) << 4);
        alo[mi] = *(const bf16x8*)(sAlo + off);
      }
      __builtin_amdgcn_s_setprio(1);
      // term-major: three passes of 16 independent MFMAs
#pragma unroll
      for (int mi = 0; mi < 4; mi++)
#pragma unroll
        for (int ni = 0; ni < 4; ni++)
          acc[mi][ni] = __builtin_amdgcn_mfma_f32_16x16x32_bf16(
              ah[mi][kf], bh[ni], acc[mi][ni], 0, 0, 0);
#pragma unroll
      for (int mi = 0; mi < 4; mi++)
#pragma unroll
        for (int ni = 0; ni < 4; ni++)
          acc[mi][ni] = __builtin_amdgcn_mfma_f32_16x16x32_bf16(
              alo[mi], bh[ni], acc[mi][ni], 0, 0, 0);
#pragma unroll
      for (int mi = 0; mi < 4; mi++)
#pragma unroll
        for (int ni = 0; ni < 4; ni++)
          acc[mi][ni] = __builtin_amdgcn_mfma_f32_16x16x32_bf16(
              ah[mi][kf], bl[ni], acc[mi][ni], 0, 0, 0);
      __builtin_amdgcn_s_setprio(0);
    }
    if (fullchunk) {
      // fast fold: tile-max + branchless ni recovery (ties -> lowest ni ->
      // lowest col; strict > across tiles keeps earliest s -> lowest col)
#pragma unroll
      for (int mi = 0; mi < 4; mi++) {
#pragma unroll
        for (int reg = 0; reg < 4; reg++) {
          const int q = mi * 4 + reg;
          const float x0 = acc[mi][0][reg], x1 = acc[mi][1][reg];
          const float x2 = acc[mi][2][reg], x3 = acc[mi][3][reg];
          const float tm = fmaxf(fmaxf(fmaxf(x0, x1), x2), x3);
          float bv = bestv[mi][reg];
          const bool win = tm > bv;
          bv = win ? tm : bv;
          const unsigned c = (x0 == tm) ? 0u : (x1 == tm) ? 1u : (x2 == tm) ? 2u : 3u;
          const unsigned code = (unsigned)(s * 4) + c;
          if (q < 8) {
            const unsigned nw = (sel0 & ~(0xFu << (q * 4))) | (code << (q * 4));
            sel0 = win ? nw : sel0;
          } else {
            const unsigned nw = (sel1 & ~(0xFu << ((q - 8) * 4))) | (code << ((q - 8) * 4));
            sel1 = win ? nw : sel1;
          }
          asm volatile("v_accvgpr_write_b32 %0, %1"
                       : "=a"(bestv[mi][reg]) : "v"(bv));
        }
#pragma unroll
        for (int ni = 0; ni < 4; ni++) acc[mi][ni] = (f32x4)(0.0f);
      }
    } else {
      // guarded fold (pad chunk only): per-candidate path
#pragma unroll
      for (int mi = 0; mi < 4; mi++) {
#pragma unroll
        for (int reg = 0; reg < 4; reg++) {
          const int q = mi * 4 + reg;
          float bv = bestv[mi][reg];
#pragma unroll
          for (int ni = 0; ni < 4; ni++) {
            const float x = acc[mi][ni][reg];
            const int col = itembase + wn * 64 + ni * 16 + lrow;
            const bool win = (col < M_ITEMS) && (x > bv);
            bv = win ? x : bv;
            const unsigned code = (unsigned)(s * 4 + ni);
            if (q < 8) {
              const unsigned nw = (sel0 & ~(0xFu << (q * 4))) | (code << (q * 4));
              sel0 = win ? nw : sel0;
            } else {
              const unsigned nw = (sel1 & ~(0xFu << ((q - 8) * 4))) | (code << ((q - 8) * 4));
              sel1 = win ? nw : sel1;
            }
          }
          asm volatile("v_accvgpr_write_b32 %0, %1"
                       : "=a"(bestv[mi][reg]) : "v"(bv));
        }
#pragma unroll
        for (int ni = 0; ni < 4; ni++) acc[mi][ni] = (f32x4)(0.0f);
      }
    }
  }
  asm volatile("s_waitcnt vmcnt(0)" ::: "memory");  // drain dummy tail prefetches

  // final fold: ONE butterfly per q; owner lane (lrow==q) keeps its row's key
  unsigned long long rb = 0ull;
#pragma unroll
  for (int mi = 0; mi < 4; mi++) {
#pragma unroll
    for (int reg = 0; reg < 4; reg++) {
      const int q = mi * 4 + reg;
      const unsigned code = (q < 8 ? (sel0 >> (q * 4)) : (sel1 >> ((q - 8) * 4))) & 0xFu;
      float v = bestv[mi][reg];
      int bi = chunk + (int)(code >> 2) * BNI + wn * 64 + (int)(code & 3) * 16 + lrow;
#pragma unroll
      for (int off = 1; off < 16; off <<= 1) {
        float ov = __shfl_xor(v, off, 16);
        int oi = __shfl_xor(bi, off, 16);
        if (ov > v || (ov == v && oi < bi)) { v = ov; bi = oi; }
      }
      if (lrow == q) rb = pack_key(v, bi);
    }
  }
  // each lane owns one distinct row of the wave's 64
  const int myrow = rowbase + wm * 64 + (lrow >> 2) * 16 + lkg * 4 + (lrow & 3);
  atomicMax(&keys[myrow], rb);
}

// ---------- kernel 7: unpack top1, gather, cosine sim ----------
__global__ void k_post(const unsigned long long* __restrict__ keys,
                       const int* __restrict__ uid,
                       const float* __restrict__ items,
                       float* __restrict__ out, float* __restrict__ sims,
                       float* __restrict__ rl) {
  int r = blockIdx.x * blockDim.x + threadIdx.x;
  if (r >= B_ROWS) return;
  unsigned long long key = keys[r];
  int idx = (int)(~(unsigned)(key & 0xFFFFFFFFull));
  out[r] = (float)idx;
  int orig = uid[2 * r + 1];
  const float* a = items + (long long)orig * D_DIM;
  const float* c = items + (long long)idx * D_DIM;
  float aa = 0.f, cc = 0.f, ac = 0.f;
#pragma unroll 4
  for (int d = 0; d < D_DIM; d++) {
    float x = a[d], y = c[d];
    aa = fmaf(x, x, aa);
    cc = fmaf(y, y, cc);
    ac = fmaf(x, y, ac);
  }
  float na = fmaxf(sqrtf(aa), COS_EPS_F);
  float nc = fmaxf(sqrtf(cc), COS_EPS_F);
  float sim = ac / (na * nc);
  sim = (sim + 1.f) * 0.5f;
  sims[r] = sim;
  rl[r] = fmaxf(sim - 0.5f, 0.f);
}

// ---------- kernel 8: deterministic final means ----------
__global__ void k_final(const float* __restrict__ sims, const float* __restrict__ rl,
                        float* __restrict__ out) {
  __shared__ float s1[256], s2[256];
  int t = threadIdx.x;
  float a = 0.f, b = 0.f;
  for (int r = t; r < B_ROWS; r += 256) { a += rl[r]; b += sims[r]; }
  s1[t] = a; s2[t] = b;
  __syncthreads();
  for (int off = 128; off; off >>= 1) {
    if (t < off) { s1[t] += s1[t + off]; s2[t] += s2[t + off]; }
    __syncthreads();
  }
  if (t == 0) {
    out[B_ROWS] = s1[0] / (float)B_ROWS;
    out[B_ROWS + 1] = s2[0] / (float)B_ROWS;
  }
}

extern "C" void kernel_launch(void* const* d_in, const int* in_sizes, int n_in,
                              void* d_out, int out_size, void* d_ws, size_t ws_size,
                              hipStream_t stream) {
  const float* item_feature = (const float*)d_in[0];
  const float* all_items    = (const float*)d_in[1];
  const int*   uid          = (const int*)d_in[2];
  const float* W            = (const float*)d_in[3];
  const float* bias         = (const float*)d_in[4];
  const float* gamma        = (const float*)d_in[5];
  const float* beta         = (const float*)d_in[6];
  float* out = (float*)d_out;

  float* h     = (float*)d_ws;             // 2048*128
  float* scale = h + B_ROWS * D_DIM;       // 128
  float* shift = scale + D_DIM;            // 128
  unsigned long long* keys = (unsigned long long*)(shift + D_DIM);  // 2048
  float* sims  = (float*)(keys + B_ROWS);  // 2048
  float* rl    = sims + B_ROWS;            // 2048

  k_gemm1<<<B_ROWS, D_DIM, 0, stream>>>(item_feature, W, bias, h);
  k_bnstats<<<D_DIM, 256, 0, stream>>>(h, gamma, beta, scale, shift);
  k_norm_split<<<(B_ROWS * D_DIM + 255) / 256, 256, 0, stream>>>(h, scale, shift);
  k_build_items<<<(M_PAD * D_DIM / 4 + 255) / 256, 256, 0, stream>>>(all_items, keys);
  const int nblk = (B_ROWS / 128) * (M_PAD / (SUPER * BNI));  // 16*196 = 3136
  k_scores_mfma<<<nblk, 256, 0, stream>>>(keys);
  k_post<<<(B_ROWS + 255) / 256, 256, 0, stream>>>(keys, uid, all_items, out, sims, rl);
  k_final<<<1, 256, 0, stream>>>(sims, rl, out);
}